// Round 9
// baseline (455.010 us; speedup 1.0000x reference)
//
#include <hip/hip_runtime.h>
#include <hip/hip_bf16.h>
#include <cstdint>
#include <cstddef>

#define D 768
#define BATCH 8
#define LC 2048
#define LQ 1024
#define SCALE 0.03608439182435161f /* 1/sqrt(768) */

typedef __attribute__((ext_vector_type(8))) short short8;
typedef __attribute__((ext_vector_type(4))) float floatx4;

__device__ __forceinline__ short f2bf(float f) {
    union { float f; uint32_t u; } v; v.f = f;
    uint32_t r = v.u + 0x7fffu + ((v.u >> 16) & 1u);
    return (short)(r >> 16);
}

// ---- async global->LDS, 16B per lane ----
__device__ __forceinline__ void gl_lds16(const short* g, short* l) {
    __builtin_amdgcn_global_load_lds(
        reinterpret_cast<const __attribute__((address_space(1))) unsigned int*>(
            reinterpret_cast<uintptr_t>(g)),
        reinterpret_cast<__attribute__((address_space(3))) unsigned int*>(
            reinterpret_cast<uintptr_t>(l)),
        16, 0, 0);
}

// ================= 128x256 core (unchanged, for gemm1) =================
__device__ __forceinline__ void gemm128x256_loop(
    const short* __restrict__ A, const short* __restrict__ B,
    int lda, int ldb, int K, int m0, int n0,
    short* lds, int tid, floatx4 acc[4][4]) {
    const int lane = tid & 63, l15 = lane & 15, quad = lane >> 4;
    const int w = tid >> 6, wm = w >> 2, wn = w & 3;

    const int ra = tid >> 2, sa = (tid & 3) ^ (ra & 3);
    const short* gA = A + (size_t)(m0 + ra) * lda + sa * 8;
    short* dA = lds + tid * 8;
    const int cb0 = tid, cb1 = tid + 512;
    const int rb0 = cb0 >> 2, sb0 = (cb0 & 3) ^ (rb0 & 3);
    const int rb1 = cb1 >> 2, sb1 = (cb1 & 3) ^ (rb1 & 3);
    const short* gB0 = B + (size_t)(n0 + rb0) * ldb + sb0 * 8;
    const short* gB1 = B + (size_t)(n0 + rb1) * ldb + sb1 * 8;
    short* dB0 = lds + 4096 + cb0 * 8;
    short* dB1 = lds + 4096 + cb1 * 8;

    int aoff[4], boff[4];
#pragma unroll
    for (int mt = 0; mt < 4; ++mt) {
        int r = wm * 64 + mt * 16 + l15;
        aoff[mt] = r * 32 + ((quad ^ (r & 3)) * 8);
    }
#pragma unroll
    for (int nt = 0; nt < 4; ++nt) {
        int r = wn * 64 + nt * 16 + l15;
        boff[nt] = 4096 + r * 32 + ((quad ^ (r & 3)) * 8);
    }

    const int NT = K >> 5;
#define STAGE_A(t, bb) { gl_lds16(gA + (t) * 32, dA + (bb)); }
#define STAGE_B(t, bb) { gl_lds16(gB0 + (t) * 32, dB0 + (bb)); gl_lds16(gB1 + (t) * 32, dB1 + (bb)); }
    STAGE_A(0, 0) STAGE_B(0, 0)
    STAGE_A(1, 12288) STAGE_B(1, 12288)

    for (int kt = 0; kt < NT; ++kt) {
        const int cur = (kt % 3) * 12288;
        const int nxt = ((kt + 2) % 3) * 12288;
        if (kt + 1 < NT) { asm volatile("s_waitcnt vmcnt(3)" ::: "memory"); }
        else             { asm volatile("s_waitcnt vmcnt(0)" ::: "memory"); }
        __builtin_amdgcn_s_barrier();
        __builtin_amdgcn_sched_barrier(0);

        if (kt + 2 < NT) STAGE_A((kt + 2), nxt)

        short8 af[4], bf[4];
#pragma unroll
        for (int mt = 0; mt < 4; ++mt)
            af[mt] = *reinterpret_cast<const short8*>(lds + cur + aoff[mt]);
#pragma unroll
        for (int nt = 0; nt < 2; ++nt)
            bf[nt] = *reinterpret_cast<const short8*>(lds + cur + boff[nt]);
        __builtin_amdgcn_s_setprio(1);
#pragma unroll
        for (int mt = 0; mt < 4; ++mt)
#pragma unroll
            for (int nt = 0; nt < 2; ++nt)
                acc[mt][nt] = __builtin_amdgcn_mfma_f32_16x16x32_bf16(af[mt], bf[nt], acc[mt][nt], 0, 0, 0);
        __builtin_amdgcn_s_setprio(0);

        if (kt + 2 < NT) STAGE_B((kt + 2), nxt)

#pragma unroll
        for (int nt = 2; nt < 4; ++nt)
            bf[nt] = *reinterpret_cast<const short8*>(lds + cur + boff[nt]);
        __builtin_amdgcn_s_setprio(1);
#pragma unroll
        for (int mt = 0; mt < 4; ++mt)
#pragma unroll
            for (int nt = 2; nt < 4; ++nt)
                acc[mt][nt] = __builtin_amdgcn_mfma_f32_16x16x32_bf16(af[mt], bf[nt], acc[mt][nt], 0, 0, 0);
        __builtin_amdgcn_s_setprio(0);
        __builtin_amdgcn_sched_barrier(0);
    }
#undef STAGE_A
#undef STAGE_B
}

// ---------------- fused prep: cast W, ctx copy+cast, qh cast+transpose ----------
__global__ __launch_bounds__(256) void prep_kernel(
    const float* __restrict__ ctx, const float* __restrict__ qh,
    const float* __restrict__ Wf, float* __restrict__ out,
    short* __restrict__ W_b, short* __restrict__ ctx_b,
    short* __restrict__ qh_b, short* __restrict__ qhT) {
    __shared__ float tile[32][33];
    const int tid = threadIdx.x;
    const int bid = blockIdx.x;
    const int gid = bid * 256 + tid;          // grid = 2048 x 256 = 524288 threads

    if (gid < 147456) {
        float4 v = reinterpret_cast<const float4*>(Wf)[gid];
        short4 o;
        o.x = f2bf(v.x); o.y = f2bf(v.y); o.z = f2bf(v.z); o.w = f2bf(v.w);
        reinterpret_cast<short4*>(W_b)[gid] = o;
    }
#pragma unroll
    for (int it = 0; it < 6; ++it) {
        int i = gid + it * 524288;
        int row = i / 192, c4 = i % 192;
        float4 v = reinterpret_cast<const float4*>(ctx)[i];
        reinterpret_cast<float4*>(out)[(size_t)row * 384 + c4] = v;
        short4 o;
        o.x = f2bf(v.x); o.y = f2bf(v.y); o.z = f2bf(v.z); o.w = f2bf(v.w);
        reinterpret_cast<short4*>(ctx_b)[i] = o;
    }
    const int r = tid >> 3, c = (tid & 7) * 4;
#pragma unroll
    for (int it = 0; it < 3; ++it) {
        const int T = bid + it * 2048;
        const int b = T / 768, rem = T % 768;
        const int q0 = (rem / 24) * 32, d0 = (rem % 24) * 32;
        const float4 v = *reinterpret_cast<const float4*>(
            qh + ((size_t)b * LQ + q0 + r) * D + d0 + c);
        tile[r][c] = v.x; tile[r][c + 1] = v.y; tile[r][c + 2] = v.z; tile[r][c + 3] = v.w;
        short4 d;
        d.x = f2bf(v.x); d.y = f2bf(v.y); d.z = f2bf(v.z); d.w = f2bf(v.w);
        *reinterpret_cast<short4*>(qh_b + ((size_t)b * LQ + q0 + r) * D + d0 + c) = d;
        __syncthreads();
        short4 o;
        o.x = f2bf(tile[c][r]); o.y = f2bf(tile[c + 1][r]);
        o.z = f2bf(tile[c + 2][r]); o.w = f2bf(tile[c + 3][r]);
        *reinterpret_cast<short4*>(qhT + ((size_t)b * D + d0 + r) * LQ + q0 + c) = o;
        __syncthreads();
    }
}

// ---------------- GEMM1: query = qh_b * W_b^T + bias -> bf16; 192 blocks -------
__global__ __launch_bounds__(512, 4) void gemm1_kernel(
    const short* __restrict__ A, const short* __restrict__ W,
    const float* __restrict__ bias, short* __restrict__ Q) {
    __shared__ __align__(16) short lds[3 * 12288];  // 72 KiB
    const int nb = (blockIdx.x & 7) * 24 + (blockIdx.x >> 3);
    const int m0 = (nb / 3) * 128, n0 = (nb % 3) * 256;
    const int tid = threadIdx.x;
    const int lane = tid & 63, l15 = lane & 15, quad = lane >> 4;
    const int w = tid >> 6, wm = w >> 2, wn = w & 3;
    floatx4 acc[4][4];
#pragma unroll
    for (int i = 0; i < 4; ++i)
#pragma unroll
        for (int j = 0; j < 4; ++j) { floatx4 z = {0.f, 0.f, 0.f, 0.f}; acc[i][j] = z; }
    gemm128x256_loop(A, W, D, D, D, m0, n0, lds, tid, acc);
    float bv[4];
#pragma unroll
    for (int nt = 0; nt < 4; ++nt) bv[nt] = bias[n0 + wn * 64 + nt * 16 + l15];
#pragma unroll
    for (int mt = 0; mt < 4; ++mt)
#pragma unroll
        for (int rr = 0; rr < 4; ++rr) {
            int row = m0 + wm * 64 + mt * 16 + quad * 4 + rr;
#pragma unroll
            for (int nt = 0; nt < 4; ++nt)
                Q[(size_t)row * D + n0 + wn * 64 + nt * 16 + l15] = f2bf(acc[mt][nt][rr] + bv[nt]);
        }
}

// ================= fused attention v4: 16 waves, LDS-staged S-B, pipelined =================
// 256 blocks (batch = bid&7 -> one batch per XCD; 32 row-blocks of 64 ctx rows), 1024 thr.
// LDS (shorts): [0,49152) ctx[64][768] swizzled persistent | [49152,57344) P[64][128]
//             | [57344,69632) q-stage 3 x [128][32] (16B-slot swz, 3-buf dist-2 vmcnt pipeline)
// = 136 KiB. rowsum4 (4x64 f32) aliased onto the q-region after the last chunk (dead then).
// Waves: 4 wm (16 ctx rows each) x 4 wn. S: sacc[2] (2 q-subtiles). PV: oacc[12] (192 d).
// Waves 0-7 stage q (1 load/thread/step -> gate vmcnt(1), tile t+1 in flight).
#define PBASE 49152
#define QBASE 57344
__global__ __launch_bounds__(1024, 4) void attn_kernel(
    const short* __restrict__ ctxb, const short* __restrict__ query_b,
    const short* __restrict__ qhT, const int* __restrict__ qmask,
    float* __restrict__ out) {
    __shared__ __align__(16) short lds[69632];  // 136 KiB
    const int tid = threadIdx.x;
    const int b = blockIdx.x & 7;
    const int m0 = (blockIdx.x >> 3) * 64;
    const int lane = tid & 63, l15 = lane & 15, quad = lane >> 4;
    const int w = tid >> 6, wm = w >> 2, wn = w & 3;   // 4x4 waves

    // ---- stage ctx[64][768] -> swizzled LDS (once), then drain ----
    const short* cbase = ctxb + ((size_t)b * LC + m0) * D;
#pragma unroll
    for (int i = 0; i < 6; ++i) {
        int cch = tid + i * 1024;
        int row = cch / 96, s = cch - row * 96;
        gl_lds16(cbase + (size_t)row * D + ((s ^ (row & 7)) * 8), lds + cch * 8);
    }
    asm volatile("s_waitcnt vmcnt(0)" ::: "memory");
    __builtin_amdgcn_s_barrier();

    const int ar = wm * 16 + l15;              // ctx/P fragment row
    const int abase = ar * 768, axor = ar & 7;
    const int pabase = PBASE + ar * 128;
    const int rq0 = wn * 32 + l15, rq1 = rq0 + 16;   // q fragment rows
    const int bo0 = rq0 * 32 + ((quad ^ (rq0 & 3)) * 8);
    const int bo1 = rq1 * 32 + ((quad ^ (rq1 & 3)) * 8);

    // q staging mapping: waves 0-7 (tid<512), 1 chunk each of the [128][32] tile
    const bool stager = (tid < 512);
    const int qr = (tid & 511) >> 2, qs = ((tid & 511) & 3) ^ (qr & 3);
    const short* qpanel = query_b + (size_t)b * LQ * D;
    short* qdst = lds + QBASE + (tid & 511) * 8;

    const short* qt = qhT + (size_t)b * D * LQ + (size_t)(wn * 192 + l15) * LQ + quad * 8;
    const int* mk = qmask + b * LQ;

    floatx4 oacc[12];
#pragma unroll
    for (int j = 0; j < 12; ++j) { floatx4 z = {0.f, 0.f, 0.f, 0.f}; oacc[j] = z; }
    float psum[4] = {0.f, 0.f, 0.f, 0.f};

    for (int ch = 0; ch < 8; ++ch) {
        const int q0 = ch * 128;
        const short* qcol = qpanel + (size_t)(q0 + qr) * D + qs * 8;
        // prologue: steps 0,1 in flight
        if (stager) {
            gl_lds16(qcol, qdst);
            gl_lds16(qcol + 32, qdst + 4096);
        }
        floatx4 sacc[2];
        { floatx4 z = {0.f, 0.f, 0.f, 0.f}; sacc[0] = z; sacc[1] = z; }
        // ---- S = ctx @ q_chunk^T : 24 steps of BK=32, 3-buf counted-vmcnt pipeline ----
#pragma unroll 3
        for (int st = 0; st < 24; ++st) {
            const int cur = QBASE + (st % 3) * 4096;
            if (st < 23) { asm volatile("s_waitcnt vmcnt(1)" ::: "memory"); }
            else         { asm volatile("s_waitcnt vmcnt(0)" ::: "memory"); }
            __builtin_amdgcn_s_barrier();
            if (stager && st + 2 < 24)
                gl_lds16(qcol + (st + 2) * 32, qdst + ((st + 2) % 3) * 4096);
            short8 af = *reinterpret_cast<const short8*>(lds + abase + (((st * 4 + quad) ^ axor) * 8));
            short8 bf0 = *reinterpret_cast<const short8*>(lds + cur + bo0);
            short8 bf1 = *reinterpret_cast<const short8*>(lds + cur + bo1);
            __builtin_amdgcn_s_setprio(1);
            sacc[0] = __builtin_amdgcn_mfma_f32_16x16x32_bf16(af, bf0, sacc[0], 0, 0, 0);
            sacc[1] = __builtin_amdgcn_mfma_f32_16x16x32_bf16(af, bf1, sacc[1], 0, 0, 0);
            __builtin_amdgcn_s_setprio(0);
        }
        // ---- epilogue: mask, exp, partial row-sum, P -> swizzled LDS ----
        bool valid0 = (mk[q0 + wn * 32 + l15] != 0);
        bool valid1 = (mk[q0 + wn * 32 + 16 + l15] != 0);
#pragma unroll
        for (int rr = 0; rr < 4; ++rr) {
            int prow = wm * 16 + quad * 4 + rr;
            float pv0 = valid0 ? __expf(sacc[0][rr] * SCALE) : 0.f;
            float pv1 = valid1 ? __expf(sacc[1][rr] * SCALE) : 0.f;
            int pc0 = wn * 32 + l15, pc1 = pc0 + 16;
            lds[PBASE + prow * 128 + ((((pc0 >> 3) ^ (prow & 7)) << 3) | (pc0 & 7))] = f2bf(pv0);
            lds[PBASE + prow * 128 + ((((pc1 >> 3) ^ (prow & 7)) << 3) | (pc1 & 7))] = f2bf(pv1);
            float rsum = pv0 + pv1;
#pragma unroll
            for (int off = 1; off < 16; off <<= 1)
                rsum += __shfl_xor(rsum, off, 64);
            psum[rr] += rsum;   // this wave's 32-col partial
        }
        asm volatile("s_waitcnt lgkmcnt(0)" ::: "memory");
        __builtin_amdgcn_sched_barrier(0);
        __builtin_amdgcn_s_barrier();
        __builtin_amdgcn_sched_barrier(0);
        // ---- PV: O += P @ qhT^T (per wave 16 rows x 192 d); bq register-direct, no barriers ----
        const short* qtc = qt + q0;
#pragma unroll
        for (int kt = 0; kt < 4; ++kt) {
            short8 pa = *reinterpret_cast<const short8*>(lds + pabase + (((kt * 4 + quad) ^ axor) * 8));
#pragma unroll
            for (int nt = 0; nt < 12; ++nt) {
                short8 bq = *reinterpret_cast<const short8*>(qtc + (size_t)nt * 16 * LQ + kt * 32);
                oacc[nt] = __builtin_amdgcn_mfma_f32_16x16x32_bf16(pa, bq, oacc[nt], 0, 0, 0);
            }
        }
        // no barrier needed: next chunk's first gate+barrier orders PV reads vs P/q overwrites
    }
    // ---- cross-wave row-sum reduction (q-region now dead -> alias rowsum4 there) ----
    float* rowsum4 = reinterpret_cast<float*>(lds + QBASE);   // [4][64]
    if (l15 == 0) {
#pragma unroll
        for (int rr = 0; rr < 4; ++rr)
            rowsum4[wn * 64 + wm * 16 + quad * 4 + rr] = psum[rr];
    }
    __syncthreads();
    // ---- normalize + write out[..., 768:1536] ----
#pragma unroll
    for (int rr = 0; rr < 4; ++rr) {
        int prow = wm * 16 + quad * 4 + rr;
        const float inv = 1.0f / (rowsum4[prow] + rowsum4[64 + prow] +
                                  rowsum4[128 + prow] + rowsum4[192 + prow]);
        size_t ro = ((size_t)b * LC + m0 + prow) * 1536 + 768;
#pragma unroll
        for (int nt = 0; nt < 12; ++nt)
            out[ro + wn * 192 + nt * 16 + l15] = oacc[nt][rr] * inv;
    }
}

extern "C" void kernel_launch(void* const* d_in, const int* in_sizes, int n_in,
                              void* d_out, int out_size, void* d_ws, size_t ws_size,
                              hipStream_t stream) {
    const float* ctx = (const float*)d_in[0];
    const float* qh = (const float*)d_in[2];
    const int* qmask = (const int*)d_in[3];
    const float* Wf = (const float*)d_in[4];
    const float* bias = (const float*)d_in[5];
    float* out = (float*)d_out;

    char* ws = (char*)d_ws;
    short* W_b     = (short*)(ws);                  //  1,179,648 B
    short* query_b = (short*)(ws + 1179648);        // 12,582,912 B
    short* qhT     = (short*)(ws + 13762560);       // 12,582,912 B
    short* ctx_b   = (short*)(ws + 26345472);       // 25,165,824 B
    short* qh_b    = (short*)(ws + 51511296);       // 12,582,912 B

    prep_kernel<<<2048, 256, 0, stream>>>(ctx, qh, Wf, out, W_b, ctx_b, qh_b, qhT);
    gemm1_kernel<<<192, 512, 0, stream>>>(qh_b, W_b, bias, query_b);
    attn_kernel<<<256, 1024, 0, stream>>>(ctx_b, query_b, qhT, qmask, out);
}

// Round 10
// 272.480 us; speedup vs baseline: 1.6699x; 1.6699x over previous
//
#include <hip/hip_runtime.h>
#include <hip/hip_bf16.h>
#include <cstdint>
#include <cstddef>

#define D 768
#define BATCH 8
#define LC 2048
#define LQ 1024
#define SCALE 0.03608439182435161f /* 1/sqrt(768) */

typedef __attribute__((ext_vector_type(8))) short short8;
typedef __attribute__((ext_vector_type(4))) float floatx4;

__device__ __forceinline__ short f2bf(float f) {
    union { float f; uint32_t u; } v; v.f = f;
    uint32_t r = v.u + 0x7fffu + ((v.u >> 16) & 1u);
    return (short)(r >> 16);
}

// ---- async global->LDS, 16B per lane ----
__device__ __forceinline__ void gl_lds16(const short* g, short* l) {
    __builtin_amdgcn_global_load_lds(
        reinterpret_cast<const __attribute__((address_space(1))) unsigned int*>(
            reinterpret_cast<uintptr_t>(g)),
        reinterpret_cast<__attribute__((address_space(3))) unsigned int*>(
            reinterpret_cast<uintptr_t>(l)),
        16, 0, 0);
}

// ================= old 128x128 core (for gemm1) — round-1 verbatim =================
__device__ __forceinline__ void stage_tile(const short* gbase, int ld, int m0, int k0,
                                           short* lds, int tid) {
    const int r = tid >> 2, kc = (tid & 3) * 8;
    gl_lds16(gbase + (size_t)(m0 + r) * ld + k0 + kc, lds + tid * 8);
    gl_lds16(gbase + (size_t)(m0 + r + 64) * ld + k0 + kc, lds + 2048 + tid * 8);
}

__device__ __forceinline__ void mfma_tile_loop(
    const short* Ab, const short* Bb, int lda, int ldb, int K, int m0, int n0,
    short* sA, short* sB, int tid, floatx4 acc[4][4]) {
    const int w = tid >> 6, lane = tid & 63, l15 = lane & 15, quad = lane >> 4;
    const int wm = (w >> 1) * 64, wn = (w & 1) * 64;
    for (int k0 = 0; k0 < K; k0 += 32) {
        stage_tile(Ab, lda, m0, k0, sA, tid);
        stage_tile(Bb, ldb, n0, k0, sB, tid);
        __syncthreads();
        short8 af[4], bf[4];
#pragma unroll
        for (int mt = 0; mt < 4; ++mt)
            af[mt] = *reinterpret_cast<const short8*>(&sA[(wm + mt * 16 + l15) * 32 + quad * 8]);
#pragma unroll
        for (int nt = 0; nt < 4; ++nt)
            bf[nt] = *reinterpret_cast<const short8*>(&sB[(wn + nt * 16 + l15) * 32 + quad * 8]);
#pragma unroll
        for (int mt = 0; mt < 4; ++mt)
#pragma unroll
            for (int nt = 0; nt < 4; ++nt)
                acc[mt][nt] = __builtin_amdgcn_mfma_f32_16x16x32_bf16(af[mt], bf[nt], acc[mt][nt], 0, 0, 0);
        __syncthreads();
    }
}

// ================= 256x256 core: BK=32, 3 buffers, free-drift counted-vmcnt =================
// round-1 verbatim (best measured: 265.8 us total).
__device__ __forceinline__ void gemm256_loop(
    const short* __restrict__ A, const short* __restrict__ B,
    int lda, int ldb, int K, int m0, int n0,
    short* lds, int tid, floatx4 acc[8][4]) {
    const int lane = tid & 63, l15 = lane & 15, quad = lane >> 4;
    const int w = tid >> 6, wm = w >> 2, wn = w & 3;

    const int c0 = tid, c1 = tid + 512;
    const int r0 = c0 >> 2, s0 = (c0 & 3) ^ (r0 & 3);
    const int r1 = c1 >> 2, s1 = (c1 & 3) ^ (r1 & 3);
    const short* gA0 = A + (size_t)(m0 + r0) * lda + s0 * 8;
    const short* gA1 = A + (size_t)(m0 + r1) * lda + s1 * 8;
    const short* gB0 = B + (size_t)(n0 + r0) * ldb + s0 * 8;
    const short* gB1 = B + (size_t)(n0 + r1) * ldb + s1 * 8;
    short* dA0 = lds + c0 * 8;
    short* dA1 = lds + c1 * 8;
    short* dB0 = lds + 8192 + c0 * 8;
    short* dB1 = lds + 8192 + c1 * 8;

    int aoff[8], boff[4];
#pragma unroll
    for (int mt = 0; mt < 8; ++mt) {
        int r = wm * 128 + mt * 16 + l15;
        aoff[mt] = r * 32 + ((quad ^ (r & 3)) * 8);
    }
#pragma unroll
    for (int nt = 0; nt < 4; ++nt) {
        int r = wn * 64 + nt * 16 + l15;
        boff[nt] = 8192 + r * 32 + ((quad ^ (r & 3)) * 8);
    }

    const int NT = K >> 5;
#define STAGE_A(t, bb) { gl_lds16(gA0 + (t) * 32, dA0 + (bb)); gl_lds16(gA1 + (t) * 32, dA1 + (bb)); }
#define STAGE_B(t, bb) { gl_lds16(gB0 + (t) * 32, dB0 + (bb)); gl_lds16(gB1 + (t) * 32, dB1 + (bb)); }
    STAGE_A(0, 0) STAGE_B(0, 0)
    STAGE_A(1, 16384) STAGE_B(1, 16384)

    for (int kt = 0; kt < NT; ++kt) {
        const int cur = (kt % 3) * 16384;
        const int nxt = ((kt + 2) % 3) * 16384;
        if (kt + 1 < NT) { asm volatile("s_waitcnt vmcnt(4)" ::: "memory"); }
        else             { asm volatile("s_waitcnt vmcnt(0)" ::: "memory"); }
        __builtin_amdgcn_s_barrier();
        __builtin_amdgcn_sched_barrier(0);

        if (kt + 2 < NT) STAGE_A((kt + 2), nxt)

        short8 af[8], bf[4];
#pragma unroll
        for (int mt = 0; mt < 8; ++mt)
            af[mt] = *reinterpret_cast<const short8*>(lds + cur + aoff[mt]);
#pragma unroll
        for (int nt = 0; nt < 2; ++nt)
            bf[nt] = *reinterpret_cast<const short8*>(lds + cur + boff[nt]);
        __builtin_amdgcn_s_setprio(1);
#pragma unroll
        for (int mt = 0; mt < 8; ++mt)
#pragma unroll
            for (int nt = 0; nt < 2; ++nt)
                acc[mt][nt] = __builtin_amdgcn_mfma_f32_16x16x32_bf16(af[mt], bf[nt], acc[mt][nt], 0, 0, 0);
        __builtin_amdgcn_s_setprio(0);

        if (kt + 2 < NT) STAGE_B((kt + 2), nxt)

#pragma unroll
        for (int nt = 2; nt < 4; ++nt)
            bf[nt] = *reinterpret_cast<const short8*>(lds + cur + boff[nt]);
        __builtin_amdgcn_s_setprio(1);
#pragma unroll
        for (int mt = 0; mt < 8; ++mt)
#pragma unroll
            for (int nt = 2; nt < 4; ++nt)
                acc[mt][nt] = __builtin_amdgcn_mfma_f32_16x16x32_bf16(af[mt], bf[nt], acc[mt][nt], 0, 0, 0);
        __builtin_amdgcn_s_setprio(0);
        __builtin_amdgcn_sched_barrier(0);
    }
#undef STAGE_A
#undef STAGE_B
}

// ---------------- fused prep (round-6 verbatim): W cast + sums zero + ctx + qh ----------
__global__ __launch_bounds__(256) void prep_kernel(
    const float* __restrict__ ctx, const float* __restrict__ qh,
    const float* __restrict__ Wf, float* __restrict__ out,
    short* __restrict__ W_b, short* __restrict__ ctx_b,
    short* __restrict__ qh_b, short* __restrict__ qhT, float* __restrict__ sums) {
    __shared__ float tile[32][33];
    const int tid = threadIdx.x;
    const int bid = blockIdx.x;
    const int gid = bid * 256 + tid;          // grid = 2048 x 256 = 524288 threads

    if (gid < 147456) {
        float4 v = reinterpret_cast<const float4*>(Wf)[gid];
        short4 o;
        o.x = f2bf(v.x); o.y = f2bf(v.y); o.z = f2bf(v.z); o.w = f2bf(v.w);
        reinterpret_cast<short4*>(W_b)[gid] = o;
    }
    if (gid < 4096) {
        float4 z = {0.f, 0.f, 0.f, 0.f};
        reinterpret_cast<float4*>(sums)[gid] = z;
    }
#pragma unroll
    for (int it = 0; it < 6; ++it) {
        int i = gid + it * 524288;
        int row = i / 192, c4 = i % 192;
        float4 v = reinterpret_cast<const float4*>(ctx)[i];
        reinterpret_cast<float4*>(out)[(size_t)row * 384 + c4] = v;
        short4 o;
        o.x = f2bf(v.x); o.y = f2bf(v.y); o.z = f2bf(v.z); o.w = f2bf(v.w);
        reinterpret_cast<short4*>(ctx_b)[i] = o;
    }
    const int r = tid >> 3, c = (tid & 7) * 4;
#pragma unroll
    for (int it = 0; it < 3; ++it) {
        const int T = bid + it * 2048;
        const int b = T / 768, rem = T % 768;
        const int q0 = (rem / 24) * 32, d0 = (rem % 24) * 32;
        const float4 v = *reinterpret_cast<const float4*>(
            qh + ((size_t)b * LQ + q0 + r) * D + d0 + c);
        tile[r][c] = v.x; tile[r][c + 1] = v.y; tile[r][c + 2] = v.z; tile[r][c + 3] = v.w;
        short4 d;
        d.x = f2bf(v.x); d.y = f2bf(v.y); d.z = f2bf(v.z); d.w = f2bf(v.w);
        *reinterpret_cast<short4*>(qh_b + ((size_t)b * LQ + q0 + r) * D + d0 + c) = d;
        __syncthreads();
        short4 o;
        o.x = f2bf(tile[c][r]); o.y = f2bf(tile[c + 1][r]);
        o.z = f2bf(tile[c + 2][r]); o.w = f2bf(tile[c + 3][r]);
        *reinterpret_cast<short4*>(qhT + ((size_t)b * D + d0 + r) * LQ + q0 + c) = o;
        __syncthreads();
    }
}

// ---------------- GEMM1 (round-1 verbatim): query = qh_b * W_b^T + bias -> bf16 ----------
__global__ __launch_bounds__(256, 2) void gemm1_kernel(
    const short* __restrict__ A, const short* __restrict__ W,
    const float* __restrict__ bias, short* __restrict__ Q) {
    __shared__ short sA[128 * 32];
    __shared__ short sB[128 * 32];
    const int m0 = blockIdx.x * 128, n0 = blockIdx.y * 128;
    const int tid = threadIdx.x;
    const int w = tid >> 6, lane = tid & 63, l15 = lane & 15, quad = lane >> 4;
    const int wm = (w >> 1) * 64, wn = (w & 1) * 64;
    floatx4 acc[4][4];
#pragma unroll
    for (int i = 0; i < 4; ++i)
#pragma unroll
        for (int j = 0; j < 4; ++j) { floatx4 z = {0.f, 0.f, 0.f, 0.f}; acc[i][j] = z; }
    mfma_tile_loop(A, W, D, D, D, m0, n0, sA, sB, tid, acc);
    float bv[4];
#pragma unroll
    for (int nt = 0; nt < 4; ++nt) bv[nt] = bias[n0 + wn + nt * 16 + l15];
#pragma unroll
    for (int mt = 0; mt < 4; ++mt)
#pragma unroll
        for (int r = 0; r < 4; ++r) {
            int row = m0 + wm + mt * 16 + quad * 4 + r;
#pragma unroll
            for (int nt = 0; nt < 4; ++nt)
                Q[(size_t)row * D + n0 + wn + nt * 16 + l15] = f2bf(acc[mt][nt][r] + bv[nt]);
        }
}

// ---------------- K1 (round-1 verbatim): P_unnorm + row sums, 256 blocks x 512 ----------
__global__ __launch_bounds__(512, 2) void scores256_kernel(
    const short* __restrict__ ctxb, const short* __restrict__ query_b,
    const int* __restrict__ qmask, short* __restrict__ P, float* __restrict__ sums) {
    __shared__ __align__(16) short lds[3 * 16384];  // 96 KiB
    const int nb = ((blockIdx.x & 7) << 5) + (blockIdx.x >> 3);
    const int b = nb >> 5, rem = nb & 31, by = rem >> 3, bx = rem & 7;
    const int m0 = bx << 8, n0 = by << 8;
    const int tid = threadIdx.x;
    const int lane = tid & 63, l15 = lane & 15, quad = lane >> 4;
    const int w = tid >> 6, wm = w >> 2, wn = w & 3;

    floatx4 acc[8][4];
#pragma unroll
    for (int i = 0; i < 8; ++i)
#pragma unroll
        for (int j = 0; j < 4; ++j) { floatx4 z = {0.f, 0.f, 0.f, 0.f}; acc[i][j] = z; }

    gemm256_loop(ctxb + (size_t)b * LC * D, query_b + (size_t)b * LQ * D,
                 D, D, D, m0, n0, lds, tid, acc);

    const int* mk = qmask + b * LQ;
    bool valid[4];
#pragma unroll
    for (int nt = 0; nt < 4; ++nt) valid[nt] = (mk[n0 + wn * 64 + nt * 16 + l15] != 0);
    short* Pb = P + (size_t)b * LC * LQ;
    float* sumb = sums + (size_t)b * LC;
#pragma unroll
    for (int mt = 0; mt < 8; ++mt)
#pragma unroll
        for (int rr = 0; rr < 4; ++rr) {
            int row = m0 + wm * 128 + mt * 16 + quad * 4 + rr;
            float psum = 0.f;
#pragma unroll
            for (int nt = 0; nt < 4; ++nt) {
                float pv = valid[nt] ? __expf(acc[mt][nt][rr] * SCALE) : 0.f;
                psum += pv;
                Pb[(size_t)row * LQ + n0 + wn * 64 + nt * 16 + l15] = f2bf(pv);
            }
#pragma unroll
            for (int off = 1; off < 16; off <<= 1)
                psum += __shfl_xor(psum, off, 64);
            if (l15 == 0)
                atomicAdd(&sumb[row], psum);
        }
}

// ---------------- K2 (round-1 verbatim): attn_out = (P * qhT^T) / rowsum ----------------
__global__ __launch_bounds__(512, 2) void gemm2_256_kernel(
    const short* __restrict__ P, const short* __restrict__ qhT,
    const float* __restrict__ sums, float* __restrict__ out) {
    __shared__ __align__(16) short lds[3 * 16384];  // 96 KiB
    const int nb = (blockIdx.x & 7) * 24 + (blockIdx.x >> 3);
    const int b = nb / 24, rem = nb % 24, by = rem >> 3, bx = rem & 7;
    const int m0 = bx << 8, n0 = by << 8;
    const int tid = threadIdx.x;
    const int lane = tid & 63, l15 = lane & 15, quad = lane >> 4;
    const int w = tid >> 6, wm = w >> 2, wn = w & 3;

    floatx4 acc[8][4];
#pragma unroll
    for (int i = 0; i < 8; ++i)
#pragma unroll
        for (int j = 0; j < 4; ++j) { floatx4 z = {0.f, 0.f, 0.f, 0.f}; acc[i][j] = z; }

    gemm256_loop(P + (size_t)b * LC * LQ, qhT + (size_t)b * D * LQ,
                 LQ, LQ, LQ, m0, n0, lds, tid, acc);

    const float* sumb = sums + (size_t)b * LC;
#pragma unroll
    for (int mt = 0; mt < 8; ++mt)
#pragma unroll
        for (int rr = 0; rr < 4; ++rr) {
            int lrow = m0 + wm * 128 + mt * 16 + quad * 4 + rr;
            const float inv = 1.0f / sumb[lrow];
            size_t rowoff = ((size_t)b * LC + lrow) * 1536 + 768;
#pragma unroll
            for (int nt = 0; nt < 4; ++nt)
                out[rowoff + n0 + wn * 64 + nt * 16 + l15] = acc[mt][nt][rr] * inv;
        }
}

extern "C" void kernel_launch(void* const* d_in, const int* in_sizes, int n_in,
                              void* d_out, int out_size, void* d_ws, size_t ws_size,
                              hipStream_t stream) {
    const float* ctx = (const float*)d_in[0];
    const float* qh = (const float*)d_in[2];
    const int* qmask = (const int*)d_in[3];
    const float* Wf = (const float*)d_in[4];
    const float* bias = (const float*)d_in[5];
    float* out = (float*)d_out;

    char* ws = (char*)d_ws;
    short* W_b     = (short*)(ws);                  //  1,179,648 B
    short* query_b = (short*)(ws + 1179648);        // 12,582,912 B
    short* qhT     = (short*)(ws + 13762560);       // 12,582,912 B
    short* ctx_b   = (short*)(ws + 26345472);       // 25,165,824 B
    short* P       = (short*)(ws + 51511296);       // 33,554,432 B
    float* sums    = (float*)(ws + 85065728);       //     65,536 B -> end 85,131,264
    short* qh_b    = (short*)(ws + 51511296);       // alias with P (dead before scores writes P)

    prep_kernel<<<2048, 256, 0, stream>>>(ctx, qh, Wf, out, W_b, ctx_b, qh_b, qhT, sums);
    gemm1_kernel<<<dim3(64, 6), 256, 0, stream>>>(qh_b, W_b, bias, query_b);
    scores256_kernel<<<dim3(256), dim3(512), 0, stream>>>(ctx_b, query_b, qmask, P, sums);
    gemm2_256_kernel<<<dim3(192), dim3(512), 0, stream>>>(P, qhT, sums, out);
}